// Round 2
// baseline (654.617 us; speedup 1.0000x reference)
//
#include <hip/hip_runtime.h>
#include <stdint.h>

// TopKAbsolutes2D: B=64 rows, N=1,048,576 elems/row, K=256.
// Pass 1: per-row 2048-bin histogram of absbits>>20 (monotone in |x|).
// Pass 2: per-row cutoff bin b* + r (how many still needed from bin b*).
// Pass 3: out = (bin>b*) ? x : 0 (zeroes everything else); collect bin==b* candidates.
// Pass 4: exact top-r among candidates (abs desc, index asc == jax top_k tie-break), scatter.
//
// R1 lesson: NEVER exceed ws_size. Previous version assumed 5.25 MiB of ws and
// (theory) overwrote an adjacent allocation (pristine input copy) -> first call
// passed, all later calls stably wrong. This version lays out 512 KiB hist +
// 1 KiB counters and derives the candidate capacity from the REAL ws_size.

#define NBINS 2048        // absbits >> 20 (8 exp bits + 3 mantissa bits)
#define ROWS  64
#define MAXCAP 2048u      // per-row candidate capacity ceiling (expect ~300)

__global__ void hist_kernel(const float* __restrict__ x, unsigned* __restrict__ hist,
                            int n_per_row, int blocks_per_row) {
    __shared__ unsigned lh[NBINS];
    for (int i = threadIdx.x; i < NBINS; i += blockDim.x) lh[i] = 0;
    __syncthreads();

    int row = blockIdx.x / blocks_per_row;
    int sub = blockIdx.x % blocks_per_row;
    int chunk = n_per_row / blocks_per_row;
    const float4* xv = (const float4*)(x + (size_t)row * n_per_row + (size_t)sub * chunk);
    int nvec = chunk / 4;
    for (int i = threadIdx.x; i < nvec; i += blockDim.x) {
        float4 v = xv[i];
        atomicAdd(&lh[(__float_as_uint(v.x) & 0x7fffffffu) >> 20], 1u);
        atomicAdd(&lh[(__float_as_uint(v.y) & 0x7fffffffu) >> 20], 1u);
        atomicAdd(&lh[(__float_as_uint(v.z) & 0x7fffffffu) >> 20], 1u);
        atomicAdd(&lh[(__float_as_uint(v.w) & 0x7fffffffu) >> 20], 1u);
    }
    __syncthreads();

    unsigned* gh = hist + (size_t)row * NBINS;
    for (int i = threadIdx.x; i < NBINS; i += blockDim.x) {
        unsigned c = lh[i];
        if (c) atomicAdd(&gh[i], c);
    }
}

// One block per row: stage hist in LDS (coalesced), serial suffix scan in LDS.
__global__ void cutoff_kernel(const unsigned* __restrict__ hist,
                              const int* __restrict__ topk,
                              unsigned* __restrict__ row_b, unsigned* __restrict__ row_r) {
    __shared__ unsigned lh[NBINS];
    int row = blockIdx.x;
    const unsigned* h = hist + (size_t)row * NBINS;
    for (int i = threadIdx.x; i < NBINS; i += blockDim.x) lh[i] = h[i];
    __syncthreads();
    if (threadIdx.x == 0) {
        unsigned K = (unsigned)(*topk);
        unsigned acc = 0;
        unsigned bstar = 0, r = K;
        for (int b = NBINS - 1; b >= 0; --b) {
            unsigned c = lh[b];
            if (acc + c >= K) { bstar = (unsigned)b; r = K - acc; break; }
            acc += c;
        }
        row_b[row] = bstar;
        row_r[row] = r;      // 1..K values still needed from bin b*
    }
}

__global__ void filter_kernel(const float* __restrict__ x, float* __restrict__ out,
                              const unsigned* __restrict__ row_b,
                              unsigned* __restrict__ cand_count,
                              uint2* __restrict__ cand, unsigned cap,
                              int row_shift, long long total_vec) {
    long long stride = (long long)gridDim.x * blockDim.x;
    for (long long g = (long long)blockIdx.x * blockDim.x + threadIdx.x;
         g < total_vec; g += stride) {
        float4 v = ((const float4*)x)[g];
        long long e0 = g * 4;
        int row = (int)(e0 >> row_shift);              // n_per_row is a power of two
        unsigned idx0 = (unsigned)(e0 - ((long long)row << row_shift));
        unsigned bstar = row_b[row];
        float in[4] = {v.x, v.y, v.z, v.w};
        float o[4];
        #pragma unroll
        for (int c = 0; c < 4; ++c) {
            unsigned bits = __float_as_uint(in[c]);
            unsigned bin  = (bits & 0x7fffffffu) >> 20;
            o[c] = (bin > bstar) ? in[c] : 0.0f;
            if (bin == bstar) {
                unsigned pos = atomicAdd(&cand_count[row], 1u);
                if (pos < cap) cand[(size_t)row * cap + pos] = make_uint2(bits, idx0 + c);
            }
        }
        ((float4*)out)[g] = make_float4(o[0], o[1], o[2], o[3]);
    }
}

__global__ void select_kernel(const unsigned* __restrict__ cand_count,
                              const uint2* __restrict__ cand, unsigned cap,
                              const unsigned* __restrict__ row_r,
                              float* __restrict__ out, int n_per_row) {
    int row = blockIdx.x;
    unsigned M = cand_count[row];
    if (M > cap) M = cap;
    unsigned r = row_r[row];
    const uint2* c = cand + (size_t)row * cap;
    for (unsigned i = threadIdx.x; i < M; i += blockDim.x) {
        uint2 ci = c[i];
        unsigned ai = ci.x & 0x7fffffffu;
        unsigned rank = 0;
        for (unsigned j = 0; j < M; ++j) {
            uint2 cj = c[j];
            unsigned aj = cj.x & 0x7fffffffu;
            rank += (unsigned)((aj > ai) || (aj == ai && cj.y < ci.y));
        }
        if (rank < r)
            out[(size_t)row * n_per_row + ci.y] = __uint_as_float(ci.x);
    }
}

extern "C" void kernel_launch(void* const* d_in, const int* in_sizes, int n_in,
                              void* d_out, int out_size, void* d_ws, size_t ws_size,
                              hipStream_t stream) {
    const float* x   = (const float*)d_in[0];
    const int* topk  = (const int*)d_in[1];
    float* out       = (float*)d_out;

    const int rows = ROWS;
    const int n_per_row = out_size / rows;             // 1,048,576 (2^20)
    int row_shift = 0;
    while ((1 << row_shift) < n_per_row) ++row_shift;  // 20

    // --- workspace layout (strictly within ws_size) ---
    uint8_t* ws = (uint8_t*)d_ws;
    size_t off = 0;
    unsigned* hist = (unsigned*)(ws + off);  off += (size_t)rows * NBINS * sizeof(unsigned); // 512 KiB
    unsigned* cand_count = (unsigned*)(ws + off); off += 256;
    unsigned* row_b      = (unsigned*)(ws + off); off += 256;
    unsigned* row_r      = (unsigned*)(ws + off); off += 256;
    off = (off + 255) & ~(size_t)255;
    size_t zero_bytes = off;                           // hist + counters must be zeroed
    size_t avail = (ws_size > off) ? (ws_size - off) : 0;
    unsigned cap = (unsigned)(avail / ((size_t)rows * sizeof(uint2)));
    if (cap > MAXCAP) cap = MAXCAP;
    if (cap == 0) cap = 1;                             // degenerate guard (ws too small)
    uint2* cand = (uint2*)(ws + off);                  // rows*cap*8 bytes, fits by construction

    // ws is poisoned 0xAA before every call — zero what we accumulate into.
    hipMemsetAsync(d_ws, 0, zero_bytes, stream);

    const int blocks_per_row = 16;
    hist_kernel<<<rows * blocks_per_row, 256, 0, stream>>>(x, hist, n_per_row, blocks_per_row);
    cutoff_kernel<<<rows, 256, 0, stream>>>(hist, topk, row_b, row_r);
    long long total_vec = (long long)rows * n_per_row / 4;
    filter_kernel<<<4096, 256, 0, stream>>>(x, out, row_b, cand_count, cand, cap,
                                            row_shift, total_vec);
    select_kernel<<<rows, 256, 0, stream>>>(cand_count, cand, cap, row_r, out, n_per_row);
}

// Round 3
// 533.760 us; speedup vs baseline: 1.2264x; 1.2264x over previous
//
#include <hip/hip_runtime.h>
#include <stdint.h>

// TopKAbsolutes2D: B=64 rows, N=1,048,576 elems/row, K=256.
// Pass 1 (hist):   per-block private 4096-bin hist of absbits>>19 (monotone in |x|),
//                  written to per-block slabs (NO global atomics).
// Pass 2 (cutoff): per-row block reduces the 8 partials, finds cutoff bin b* and
//                  r = K - count_above (how many still needed from bin b*).
// Pass 3 (filter): out = (bin>b*) ? x : 0  (zeroes everything else, full 256 MB write);
//                  bin==b* elements appended to per-row candidate list (~125 expected).
// Pass 4 (select): exact top-r among candidates (abs desc, index asc — matches
//                  jax.lax.top_k tie-breaking), scatter into out.
//
// Discipline: all ws usage derived from ws_size; nothing accumulates across calls
// (cand_count zeroed via 256-B memset; partials/row_b/row_r fully overwritten).

#define NBINS 4096        // absbits >> 19 : 8 exp bits + 4 mantissa bits
#define ROWS  64
#define HBLK  8           // hist blocks per row
#define FBLK  32          // filter blocks per row
#define MAXCAP 16384u     // per-row candidate capacity ceiling (expect ~125)
#define LDS_SEL 2048      // select stages candidates in LDS when M <= this

__global__ void hist_kernel(const float* __restrict__ x, unsigned* __restrict__ parts,
                            int n_per_row) {
    __shared__ unsigned lh[NBINS];
    for (int i = threadIdx.x; i < NBINS; i += blockDim.x) lh[i] = 0;
    __syncthreads();

    int row = blockIdx.x / HBLK;
    int sub = blockIdx.x % HBLK;
    int chunk = n_per_row / HBLK;                       // 131072 elems
    const float4* xv = (const float4*)(x + (size_t)row * n_per_row + (size_t)sub * chunk);
    int nvec = chunk / 4;
    for (int i = threadIdx.x; i < nvec; i += blockDim.x) {
        float4 v = xv[i];
        atomicAdd(&lh[(__float_as_uint(v.x) & 0x7fffffffu) >> 19], 1u);
        atomicAdd(&lh[(__float_as_uint(v.y) & 0x7fffffffu) >> 19], 1u);
        atomicAdd(&lh[(__float_as_uint(v.z) & 0x7fffffffu) >> 19], 1u);
        atomicAdd(&lh[(__float_as_uint(v.w) & 0x7fffffffu) >> 19], 1u);
    }
    __syncthreads();

    unsigned* gp = parts + (size_t)blockIdx.x * NBINS;  // plain stores, no atomics
    for (int i = threadIdx.x; i < NBINS; i += blockDim.x) gp[i] = lh[i];
}

// One block (256 threads) per row.
__global__ void cutoff_kernel(const unsigned* __restrict__ parts,
                              const int* __restrict__ topk,
                              unsigned* __restrict__ row_b, unsigned* __restrict__ row_r) {
    __shared__ unsigned h[NBINS];
    __shared__ unsigned csum[256];
    int row = blockIdx.x;
    const unsigned* base = parts + (size_t)row * HBLK * NBINS;
    for (int i = threadIdx.x; i < NBINS; i += blockDim.x) {
        unsigned s = 0;
        #pragma unroll
        for (int p = 0; p < HBLK; ++p) s += base[(size_t)p * NBINS + i];
        h[i] = s;
    }
    __syncthreads();

    const int CHUNK = NBINS / 256;                      // 16 bins per thread
    unsigned cs = 0;
    int cbase = threadIdx.x * CHUNK;
    #pragma unroll
    for (int j = 0; j < CHUNK; ++j) cs += h[cbase + j];
    csum[threadIdx.x] = cs;
    __syncthreads();

    if (threadIdx.x == 0) {
        unsigned K = (unsigned)(*topk);
        unsigned acc = 0;
        int chunk = 255;
        for (; chunk > 0; --chunk) {
            if (acc + csum[chunk] >= K) break;
            acc += csum[chunk];
        }
        unsigned bstar = (unsigned)(chunk * CHUNK);
        for (int b = chunk * CHUNK + CHUNK - 1; b >= chunk * CHUNK; --b) {
            unsigned c = h[b];
            if (acc + c >= K) { bstar = (unsigned)b; break; }
            acc += c;
        }
        row_b[row] = bstar;
        row_r[row] = K - acc;    // acc = count strictly above bin b*
    }
}

__global__ void filter_kernel(const float* __restrict__ x, float* __restrict__ out,
                              const unsigned* __restrict__ row_b,
                              unsigned* __restrict__ cand_count,
                              uint2* __restrict__ cand, unsigned cap,
                              int n_per_row) {
    int row = blockIdx.x / FBLK;
    int sub = blockIdx.x % FBLK;
    int chunk = n_per_row / FBLK;                       // 32768 elems
    size_t base_e = (size_t)row * n_per_row + (size_t)sub * chunk;
    const float4* xv = (const float4*)(x + base_e);
    float4* ov = (float4*)(out + base_e);
    unsigned idx_base = (unsigned)(sub * chunk);
    unsigned bstar = row_b[row];                        // wave-uniform scalar
    int nvec = chunk / 4;
    for (int i = threadIdx.x; i < nvec; i += blockDim.x) {
        float4 v = xv[i];
        float in[4] = {v.x, v.y, v.z, v.w};
        float o[4];
        #pragma unroll
        for (int c = 0; c < 4; ++c) {
            unsigned bits = __float_as_uint(in[c]);
            unsigned bin  = (bits & 0x7fffffffu) >> 19;
            o[c] = (bin > bstar) ? in[c] : 0.0f;
            if (bin == bstar) {
                unsigned pos = atomicAdd(&cand_count[row], 1u);
                if (pos < cap) cand[(size_t)row * cap + pos] =
                    make_uint2(bits, idx_base + (unsigned)i * 4u + (unsigned)c);
            }
        }
        ov[i] = make_float4(o[0], o[1], o[2], o[3]);
    }
}

__global__ void select_kernel(const unsigned* __restrict__ cand_count,
                              const uint2* __restrict__ cand, unsigned cap,
                              const unsigned* __restrict__ row_r,
                              float* __restrict__ out, int n_per_row) {
    __shared__ uint2 lc[LDS_SEL];
    int row = blockIdx.x;
    unsigned M = cand_count[row];
    if (M > cap) M = cap;
    unsigned r = row_r[row];
    const uint2* c = cand + (size_t)row * cap;
    if (M <= LDS_SEL) {
        for (unsigned i = threadIdx.x; i < M; i += blockDim.x) lc[i] = c[i];
        __syncthreads();
        for (unsigned i = threadIdx.x; i < M; i += blockDim.x) {
            uint2 ci = lc[i];
            unsigned ai = ci.x & 0x7fffffffu;
            unsigned rank = 0;
            for (unsigned j = 0; j < M; ++j) {
                uint2 cj = lc[j];
                unsigned aj = cj.x & 0x7fffffffu;
                rank += (unsigned)((aj > ai) || (aj == ai && cj.y < ci.y));
            }
            if (rank < r)
                out[(size_t)row * n_per_row + ci.y] = __uint_as_float(ci.x);
        }
    } else {
        for (unsigned i = threadIdx.x; i < M; i += blockDim.x) {
            uint2 ci = c[i];
            unsigned ai = ci.x & 0x7fffffffu;
            unsigned rank = 0;
            for (unsigned j = 0; j < M; ++j) {
                uint2 cj = c[j];
                unsigned aj = cj.x & 0x7fffffffu;
                rank += (unsigned)((aj > ai) || (aj == ai && cj.y < ci.y));
            }
            if (rank < r)
                out[(size_t)row * n_per_row + ci.y] = __uint_as_float(ci.x);
        }
    }
}

extern "C" void kernel_launch(void* const* d_in, const int* in_sizes, int n_in,
                              void* d_out, int out_size, void* d_ws, size_t ws_size,
                              hipStream_t stream) {
    const float* x   = (const float*)d_in[0];
    const int* topk  = (const int*)d_in[1];
    float* out       = (float*)d_out;

    const int rows = ROWS;
    const int n_per_row = out_size / rows;              // 1,048,576

    // --- workspace layout (strictly within ws_size) ---
    uint8_t* ws = (uint8_t*)d_ws;
    size_t off = 0;
    unsigned* parts = (unsigned*)(ws + off);
    off += (size_t)rows * HBLK * NBINS * sizeof(unsigned);        // 8 MiB
    unsigned* cand_count = (unsigned*)(ws + off); off += 256;     // 64*4 B, zeroed
    unsigned* row_b      = (unsigned*)(ws + off); off += 256;
    unsigned* row_r      = (unsigned*)(ws + off); off += 256;
    off = (off + 255) & ~(size_t)255;
    size_t avail = (ws_size > off) ? (ws_size - off) : 0;
    unsigned cap = (unsigned)(avail / ((size_t)rows * sizeof(uint2)));
    if (cap > MAXCAP) cap = MAXCAP;
    if (cap == 0) cap = 1;                                        // degenerate guard
    uint2* cand = (uint2*)(ws + off);                             // fits by construction

    // Only cand_count accumulates — zero just those 256 bytes.
    hipMemsetAsync((void*)cand_count, 0, 256, stream);

    hist_kernel<<<rows * HBLK, 512, 0, stream>>>(x, parts, n_per_row);
    cutoff_kernel<<<rows, 256, 0, stream>>>(parts, topk, row_b, row_r);
    filter_kernel<<<rows * FBLK, 256, 0, stream>>>(x, out, row_b, cand_count, cand,
                                                   cap, n_per_row);
    select_kernel<<<rows, 256, 0, stream>>>(cand_count, cand, cap, row_r, out, n_per_row);
}